// Round 2
// baseline (914.489 us; speedup 1.0000x reference)
//
#include <hip/hip_runtime.h>

typedef __bf16 bf16x8 __attribute__((ext_vector_type(8)));
typedef __bf16 bf16x4 __attribute__((ext_vector_type(4)));
typedef float  f32x4  __attribute__((ext_vector_type(4)));

#define MFMA16(a,b,c) __builtin_amdgcn_mfma_f32_16x16x32_bf16((a),(b),(c),0,0,0)

constexpr int B_ = 256, T_ = 200, DM = 2048, DK = 128;
constexpr int VT_STRIDE = 208;      // Vt[b][v][t], t padded 200->208

// ws layout (bytes)
constexpr size_t OFF_W = 0;                       // Wcat bf16 [384][2048] = 1,572,864
constexpr size_t OFF_Q = 1572864;                 // Q bf16 [51200][128] = 13,107,200
constexpr size_t OFF_K = OFF_Q + 13107200;        // K bf16 [51200][128]
constexpr size_t OFF_V = OFF_K + 13107200;        // Vt bf16 [256][128][208] = 13,631,488

// ---------------- weight conversion: Wq|Wk|Wv fp32 -> Wcat bf16 [384][2048] ----------------
__global__ __launch_bounds__(256) void wconv_kernel(const float* __restrict__ Wq,
                                                    const float* __restrict__ Wk,
                                                    const float* __restrict__ Wv,
                                                    __bf16* __restrict__ Wcat) {
  int idx = (blockIdx.x * 256 + threadIdx.x) * 4;   // < 384*2048 = 786432
  int sel = idx >> 18;                              // /262144 -> 0,1,2
  const float* base = (sel == 0) ? Wq : (sel == 1) ? Wk : Wv;
  float4 f = *(const float4*)(base + (idx - (sel << 18)));
  bf16x4 o;
  o[0] = (__bf16)f.x; o[1] = (__bf16)f.y; o[2] = (__bf16)f.z; o[3] = (__bf16)f.w;
  *(bf16x4*)(Wcat + idx) = o;
}

// ---------------- projection GEMM: C[51200][384] = q(fp32->bf16) @ Wcat^T ----------------
// BM=128, BN=384 (full N so q is read exactly once), BK=64, 512 threads (8 waves, 2m x 4n)
// T14 register-prefetch: loads for tile k+1 issued before MFMA(k), consumed post-barrier.
__global__ __launch_bounds__(512, 4) void proj_kernel(const float* __restrict__ q,
                                                      const __bf16* __restrict__ Wcat,
                                                      __bf16* __restrict__ Qo,
                                                      __bf16* __restrict__ Ko,
                                                      __bf16* __restrict__ Vt) {
  constexpr int SAS = 68;   // LDS row stride (elems): 136B = 34 dwords -> 2*row mod 32 banks, conflict-free frag reads
  constexpr int SBS = 68;
  __shared__ __bf16 sA[128][SAS];   // 17,408 B
  __shared__ __bf16 sB[384][SBS];   // 52,224 B  (total 69,632 B -> 2 blocks/CU)

  const int tid  = threadIdx.x;
  const int lane = tid & 63;
  const int w    = tid >> 6;
  const int wm   = w >> 2, wn = w & 3;
  const int lhi  = lane >> 4, llo = lane & 15;
  const int m0   = blockIdx.x * 128;

  f32x4 acc[4][6];
#pragma unroll
  for (int i = 0; i < 4; ++i)
#pragma unroll
    for (int j = 0; j < 6; ++j) acc[i][j] = {0.f, 0.f, 0.f, 0.f};

  const int arow = tid >> 2, aseg = tid & 3;          // 128 rows x 4 segs of 16 floats
  const float* aptr = q + (size_t)(m0 + arow) * DM + aseg * 16;
  const int brow = tid >> 3, bcc = (tid & 7) * 8;     // 64 rows/round x 8 chunks of 8 bf16
  const __bf16* bptr = Wcat + (size_t)brow * DM + bcc;

  float4 fa[4];       // prefetched A (fp32)
  bf16x8 fb[6];       // prefetched B

#define ISSUE_LOADS(K0)                                                   \
  {                                                                       \
    const float4* s4 = (const float4*)(aptr + (K0));                      \
    fa[0] = s4[0]; fa[1] = s4[1]; fa[2] = s4[2]; fa[3] = s4[3];           \
    _Pragma("unroll")                                                     \
    for (int j = 0; j < 6; ++j)                                           \
      fb[j] = *(const bf16x8*)(bptr + (size_t)j * 64 * DM + (K0));        \
  }

  ISSUE_LOADS(0);

  for (int k0 = 0; k0 < DM; k0 += 64) {
    { // convert + write A (vmcnt wait lands here; loads had the whole MFMA phase to fly)
      bf16x8 p0, p1;
      p0[0]=(__bf16)fa[0].x; p0[1]=(__bf16)fa[0].y; p0[2]=(__bf16)fa[0].z; p0[3]=(__bf16)fa[0].w;
      p0[4]=(__bf16)fa[1].x; p0[5]=(__bf16)fa[1].y; p0[6]=(__bf16)fa[1].z; p0[7]=(__bf16)fa[1].w;
      p1[0]=(__bf16)fa[2].x; p1[1]=(__bf16)fa[2].y; p1[2]=(__bf16)fa[2].z; p1[3]=(__bf16)fa[2].w;
      p1[4]=(__bf16)fa[3].x; p1[5]=(__bf16)fa[3].y; p1[6]=(__bf16)fa[3].z; p1[7]=(__bf16)fa[3].w;
      *(bf16x8*)&sA[arow][aseg * 16]     = p0;
      *(bf16x8*)&sA[arow][aseg * 16 + 8] = p1;
    }
#pragma unroll
    for (int j = 0; j < 6; ++j)
      *(bf16x8*)&sB[brow + j * 64][bcc] = fb[j];
    __syncthreads();

    if (k0 + 64 < DM) ISSUE_LOADS(k0 + 64);   // in flight during MFMA + barrier

#pragma unroll
    for (int kk = 0; kk < 2; ++kk) {
      const int klo = kk * 32 + lhi * 8;
      bf16x8 af[4], bfr[6];
#pragma unroll
      for (int i = 0; i < 4; ++i) af[i]  = *(const bf16x8*)&sA[wm * 64 + i * 16 + llo][klo];
#pragma unroll
      for (int j = 0; j < 6; ++j) bfr[j] = *(const bf16x8*)&sB[wn * 96 + j * 16 + llo][klo];
#pragma unroll
      for (int i = 0; i < 4; ++i)
#pragma unroll
        for (int j = 0; j < 6; ++j) acc[i][j] = MFMA16(af[i], bfr[j], acc[i][j]);
    }
    __syncthreads();
  }
#undef ISSUE_LOADS

  // epilogue: col<128 -> Q, <256 -> K, else -> Vt transposed per batch
#pragma unroll
  for (int i = 0; i < 4; ++i) {
#pragma unroll
    for (int r = 0; r < 4; ++r) {
      int row = m0 + wm * 64 + i * 16 + lhi * 4 + r;   // bt index, always < 51200
      int b = row / 200;
      int t = row - b * 200;
#pragma unroll
      for (int j = 0; j < 6; ++j) {
        int col = wn * 96 + j * 16 + llo;
        __bf16 bv = (__bf16)acc[i][j][r];
        if (col < 128)       Qo[(size_t)row * DK + col] = bv;
        else if (col < 256)  Ko[(size_t)row * DK + (col - 128)] = bv;
        else                 Vt[((size_t)b * DK + (col - 256)) * VT_STRIDE + t] = bv;
      }
    }
  }
}

// ---------------- attention: one WG per (batch, 64-query block), templated on block ----------------
template <int QB>
__global__ __launch_bounds__(256, 1) void attn_kernel(const __bf16* __restrict__ Qg,
                                                      const __bf16* __restrict__ Kg,
                                                      const __bf16* __restrict__ Vt,
                                                      const int* __restrict__ padm,
                                                      float* __restrict__ out) {
  constexpr int Q0     = QB * 64;
  constexpr int KMAX   = (Q0 + 64 < T_) ? (Q0 + 64) : T_;   // 64,128,192,200 (causal bound)
  constexpr int KTILES = (KMAX + 15) / 16;                  // 4,8,12,13
  constexpr int KCC    = (KMAX + 31) / 32;                  // 2,4,6,7
  constexpr int KT16   = KTILES * 16;                       // 64,128,192,208
  constexpr int KP     = KCC * 32;                          // 64,128,192,224
  constexpr int VS     = KP + 8;                            // padded stride (bank spread)

  __shared__ __bf16 sK[KT16][136];
  __shared__ __bf16 sV[128][VS];       // V^T: [v][t]
  __shared__ __bf16 sP[4][16][VS];     // per-wave P transpose buffer
  __shared__ float  sMask[KT16];

  const int tid  = threadIdx.x;
  const int lane = tid & 63;
  const int w    = tid >> 6;
  const int b    = blockIdx.x;
  const int lhi  = lane >> 4, llo = lane & 15;

  // additive key mask: 0 valid, -1e30 for pad / t>=KMAX
  for (int t = tid; t < KT16; t += 256) {
    float mv = -1e30f;
    if (t < KMAX && padm[b * T_ + t] == 0) mv = 0.0f;
    sMask[t] = mv;
  }
  // stage K rows [0, KT16) (rows >= T_ clamped; they get masked anyway)
  for (int cid = tid; cid < KT16 * 16; cid += 256) {
    int t = cid >> 4, c = (cid & 15) * 8;
    int tg = (t < T_) ? t : (T_ - 1);
    *(bf16x8*)&sK[t][c] = *(const bf16x8*)(Kg + ((size_t)b * T_ + tg) * DK + c);
  }
  // stage V^T: [128][KP), zeros beyond Vt's 208 columns
  {
    constexpr int NCH = KP / 8;
    for (int cid = tid; cid < 128 * NCH; cid += 256) {
      int v = cid / NCH, t0 = (cid % NCH) * 8;
      bf16x8 val;
      if (t0 < VT_STRIDE) {
        val = *(const bf16x8*)(Vt + ((size_t)b * DK + v) * VT_STRIDE + t0);
      } else {
#pragma unroll
        for (int jz = 0; jz < 8; ++jz) val[jz] = (__bf16)0.0f;
      }
      *(bf16x8*)&sV[v][t0] = val;
    }
  }
  // zero P pad columns [KT16, KP) (only QB==3: 208..224)
  if constexpr (KT16 < KP) {
    constexpr int NC = (KP - KT16) / 8;
    for (int idx = tid; idx < 4 * 16 * NC; idx += 256) {
      int ww = idx / (16 * NC);
      int rem = idx % (16 * NC);
      int row = rem / NC, cc = (rem % NC) * 8;
      bf16x8 z;
#pragma unroll
      for (int jz = 0; jz < 8; ++jz) z[jz] = (__bf16)0.0f;
      *(bf16x8*)&sP[ww][row][KT16 + cc] = z;
    }
  }
  __syncthreads();

  // Q fragments in registers (A-frag: row = llo, k-chunk = lhi)
  const int q0w = Q0 + w * 16;
  bf16x8 qf[4];
  {
    int qrow = q0w + llo;
    if (qrow > T_ - 1) qrow = T_ - 1;
    const __bf16* qp = Qg + ((size_t)b * T_ + qrow) * DK + lhi * 8;
#pragma unroll
    for (int kk = 0; kk < 4; ++kk) qf[kk] = *(const bf16x8*)(qp + kk * 32);
  }

  // scores: S[16q x KT16] per wave, kept in registers
  float sc[KTILES][4];
  const float scale = 0.022097086912079608f;   // 1/sqrt(2048)
#pragma unroll
  for (int tt = 0; tt < KTILES; ++tt) {
    f32x4 s = {0.f, 0.f, 0.f, 0.f};
    const __bf16* kp = &sK[tt * 16 + llo][lhi * 8];
#pragma unroll
    for (int kk = 0; kk < 4; ++kk) {
      bf16x8 kf = *(const bf16x8*)(kp + kk * 32);
      s = MFMA16(qf[kk], kf, s);
    }
    const int t = tt * 16 + llo;
    const float madd = sMask[t];
#pragma unroll
    for (int r = 0; r < 4; ++r) {
      int qq = q0w + lhi * 4 + r;               // C layout: row = lhi*4+r, col = llo
      float v = fmaf(s[r], scale, madd);
      sc[tt][r] = (t > qq) ? -1e30f : v;        // overwrite-style causal mask (NaN-safe)
    }
  }

  // row softmax: reduce across the 16-lane col group per accumulator row
#pragma unroll
  for (int r = 0; r < 4; ++r) {
    float mm = -3e38f;
#pragma unroll
    for (int tt = 0; tt < KTILES; ++tt) mm = fmaxf(mm, sc[tt][r]);
#pragma unroll
    for (int off = 1; off < 16; off <<= 1) mm = fmaxf(mm, __shfl_xor(mm, off));
    float ss = 0.f;
#pragma unroll
    for (int tt = 0; tt < KTILES; ++tt) { float e = __expf(sc[tt][r] - mm); sc[tt][r] = e; ss += e; }
#pragma unroll
    for (int off = 1; off < 16; off <<= 1) ss += __shfl_xor(ss, off);
    float inv = 1.0f / ss;
#pragma unroll
    for (int tt = 0; tt < KTILES; ++tt) sc[tt][r] *= inv;
  }

  // P -> LDS (transpose through memory for the PV A-fragment)
#pragma unroll
  for (int tt = 0; tt < KTILES; ++tt) {
    int t = tt * 16 + llo;
#pragma unroll
    for (int r = 0; r < 4; ++r) sP[w][lhi * 4 + r][t] = (__bf16)sc[tt][r];
  }
  __syncthreads();

  // PV: out[16q x 128v] = P[16 x KP] @ V[KP x 128]
  f32x4 oacc[8];
#pragma unroll
  for (int vt = 0; vt < 8; ++vt) oacc[vt] = {0.f, 0.f, 0.f, 0.f};
#pragma unroll
  for (int kc = 0; kc < KCC; ++kc) {
    bf16x8 pa = *(const bf16x8*)&sP[w][llo][kc * 32 + lhi * 8];
#pragma unroll
    for (int vt = 0; vt < 8; ++vt) {
      bf16x8 vb = *(const bf16x8*)&sV[vt * 16 + llo][kc * 32 + lhi * 8];
      oacc[vt] = MFMA16(pa, vb, oacc[vt]);
    }
  }

  // write fp32 output
#pragma unroll
  for (int vt = 0; vt < 8; ++vt) {
#pragma unroll
    for (int r = 0; r < 4; ++r) {
      int qq = q0w + lhi * 4 + r;
      if (qq < T_) out[((size_t)b * T_ + qq) * DK + vt * 16 + llo] = oacc[vt][r];
    }
  }
}

extern "C" void kernel_launch(void* const* d_in, const int* in_sizes, int n_in,
                              void* d_out, int out_size, void* d_ws, size_t ws_size,
                              hipStream_t stream) {
  const float* q    = (const float*)d_in[0];
  const int*   padm = (const int*)d_in[1];
  const float* Wq   = (const float*)d_in[2];
  const float* Wk   = (const float*)d_in[3];
  const float* Wv   = (const float*)d_in[4];
  float* out        = (float*)d_out;

  char* ws = (char*)d_ws;
  __bf16* Wcat = (__bf16*)(ws + OFF_W);
  __bf16* Qb   = (__bf16*)(ws + OFF_Q);
  __bf16* Kb   = (__bf16*)(ws + OFF_K);
  __bf16* Vtb  = (__bf16*)(ws + OFF_V);

  wconv_kernel<<<768, 256, 0, stream>>>(Wq, Wk, Wv, Wcat);
  proj_kernel<<<400, 512, 0, stream>>>(q, Wcat, Qb, Kb, Vtb);
  attn_kernel<0><<<256, 256, 0, stream>>>(Qb, Kb, Vtb, padm, out);
  attn_kernel<1><<<256, 256, 0, stream>>>(Qb, Kb, Vtb, padm, out);
  attn_kernel<2><<<256, 256, 0, stream>>>(Qb, Kb, Vtb, padm, out);
  attn_kernel<3><<<256, 256, 0, stream>>>(Qb, Kb, Vtb, padm, out);
}

// Round 3
// 269.141 us; speedup vs baseline: 3.3978x; 3.3978x over previous
//
#include <hip/hip_runtime.h>

typedef __bf16 bf16x8 __attribute__((ext_vector_type(8)));
typedef __bf16 bf16x4 __attribute__((ext_vector_type(4)));
typedef float  f32x4  __attribute__((ext_vector_type(4)));

#define MFMA16(a,b,c) __builtin_amdgcn_mfma_f32_16x16x32_bf16((a),(b),(c),0,0,0)

constexpr int B_ = 256, T_ = 200, DM = 2048, DK = 128;
constexpr int VT_STRIDE = 208;      // Vt[b][v][t], t padded 200->208

// ws layout (bytes)
constexpr size_t OFF_W = 0;                       // Wcat bf16 [384][2048] = 1,572,864
constexpr size_t OFF_Q = 1572864;                 // Q bf16 [51200][128] = 13,107,200
constexpr size_t OFF_K = OFF_Q + 13107200;        // K bf16 [51200][128]
constexpr size_t OFF_V = OFF_K + 13107200;        // Vt bf16 [256][128][208] = 13,631,488

// ---------------- weight conversion: Wq|Wk|Wv fp32 -> Wcat bf16 [384][2048] ----------------
__global__ __launch_bounds__(256) void wconv_kernel(const float* __restrict__ Wq,
                                                    const float* __restrict__ Wk,
                                                    const float* __restrict__ Wv,
                                                    __bf16* __restrict__ Wcat) {
  int idx = (blockIdx.x * 256 + threadIdx.x) * 4;   // < 384*2048 = 786432
  int sel = idx >> 18;                              // /262144 -> 0,1,2
  const float* base = (sel == 0) ? Wq : (sel == 1) ? Wk : Wv;
  float4 f = *(const float4*)(base + (idx - (sel << 18)));
  bf16x4 o;
  o[0] = (__bf16)f.x; o[1] = (__bf16)f.y; o[2] = (__bf16)f.z; o[3] = (__bf16)f.w;
  *(bf16x4*)(Wcat + idx) = o;
}

// ---------------- projection GEMM: C[51200][384] = q(fp32->bf16) @ Wcat^T ----------------
// BM=128, BN=384 (full N so q HBM-read exactly once), BK=32, 512 threads (8 waves, 2m x 4n).
// Double-buffered LDS (exactly 64 KiB) + 1-deep register prefetch, ONE barrier per K-step.
// [row][32] bf16 LDS rows (64 B) are bank-conflict-free for both the stage writes and the
// frag reads: each wave's 64 lanes cover the full 16-row x 4-granule grid -> uniform banks.
__global__ __launch_bounds__(512) void proj_kernel(const float* __restrict__ q,
                                                   const __bf16* __restrict__ Wcat,
                                                   __bf16* __restrict__ Qo,
                                                   __bf16* __restrict__ Ko,
                                                   __bf16* __restrict__ Vt) {
  __shared__ __bf16 sA[2][128][32];   // 16,384 B
  __shared__ __bf16 sB[2][384][32];   // 49,152 B  (total 65,536 B)

  const int tid  = threadIdx.x;
  const int lane = tid & 63;
  const int w    = tid >> 6;
  const int wm   = w >> 2, wn = w & 3;
  const int lhi  = lane >> 4, llo = lane & 15;
  const int m0   = blockIdx.x * 128;

  f32x4 acc[4][6];
#pragma unroll
  for (int i = 0; i < 4; ++i)
#pragma unroll
    for (int j = 0; j < 6; ++j) acc[i][j] = {0.f, 0.f, 0.f, 0.f};

  // A staging: 128 rows x 32 floats / 512 threads = 8 floats (2 float4) per thread
  const int arow = tid >> 2, aseg = tid & 3;          // row, 8-float segment
  const float* aptr = q + (size_t)(m0 + arow) * DM + aseg * 8;
  // B staging: 384 rows x 32 bf16 = 1536 chunks of 8 bf16; 3 chunks per thread
  int brow[3], bcol[3];
#pragma unroll
  for (int j = 0; j < 3; ++j) {
    int c = tid + j * 512;
    brow[j] = c >> 2; bcol[j] = (c & 3) * 8;
  }

  float4 fa0, fa1;    // prefetched A (8 fp32)
  bf16x8 fb[3];       // prefetched B

#define ISSUE_LOADS(K0)                                                     \
  {                                                                         \
    const float4* s4 = (const float4*)(aptr + (K0));                        \
    fa0 = s4[0]; fa1 = s4[1];                                               \
    _Pragma("unroll")                                                       \
    for (int j = 0; j < 3; ++j)                                             \
      fb[j] = *(const bf16x8*)(Wcat + (size_t)brow[j] * DM + (K0) + bcol[j]); \
  }

#define WRITE_TILE(BUF)                                                     \
  {                                                                         \
    bf16x8 p;                                                               \
    p[0]=(__bf16)fa0.x; p[1]=(__bf16)fa0.y; p[2]=(__bf16)fa0.z; p[3]=(__bf16)fa0.w; \
    p[4]=(__bf16)fa1.x; p[5]=(__bf16)fa1.y; p[6]=(__bf16)fa1.z; p[7]=(__bf16)fa1.w; \
    *(bf16x8*)&sA[BUF][arow][aseg * 8] = p;                                 \
    _Pragma("unroll")                                                       \
    for (int j = 0; j < 3; ++j)                                             \
      *(bf16x8*)&sB[BUF][brow[j]][bcol[j]] = fb[j];                         \
  }

  constexpr int NK = DM / 32;   // 64 K-steps
  ISSUE_LOADS(0);
  WRITE_TILE(0);
  __syncthreads();

  for (int it = 0; it < NK; ++it) {
    const int buf = it & 1;
    if (it + 1 < NK) ISSUE_LOADS((it + 1) * 32);   // fly across the MFMA phase

    bf16x8 af[4], bfr[6];
#pragma unroll
    for (int i = 0; i < 4; ++i) af[i]  = *(const bf16x8*)&sA[buf][wm * 64 + i * 16 + llo][lhi * 8];
#pragma unroll
    for (int j = 0; j < 6; ++j) bfr[j] = *(const bf16x8*)&sB[buf][wn * 96 + j * 16 + llo][lhi * 8];
#pragma unroll
    for (int i = 0; i < 4; ++i)
#pragma unroll
      for (int j = 0; j < 6; ++j) acc[i][j] = MFMA16(af[i], bfr[j], acc[i][j]);

    if (it + 1 < NK) WRITE_TILE(buf ^ 1);          // vmcnt wait lands here, post-MFMA
    __syncthreads();
  }
#undef ISSUE_LOADS
#undef WRITE_TILE

  // epilogue: col<128 -> Q, <256 -> K, else -> Vt transposed per batch
#pragma unroll
  for (int i = 0; i < 4; ++i) {
#pragma unroll
    for (int r = 0; r < 4; ++r) {
      int row = m0 + wm * 64 + i * 16 + lhi * 4 + r;   // bt index, always < 51200
      int b = row / 200;
      int t = row - b * 200;
#pragma unroll
      for (int j = 0; j < 6; ++j) {
        int col = wn * 96 + j * 16 + llo;
        __bf16 bv = (__bf16)acc[i][j][r];
        if (col < 128)       Qo[(size_t)row * DK + col] = bv;
        else if (col < 256)  Ko[(size_t)row * DK + (col - 128)] = bv;
        else                 Vt[((size_t)b * DK + (col - 256)) * VT_STRIDE + t] = bv;
      }
    }
  }
}

// ---------------- attention: one WG per (batch, 64-query block), templated on block ----------------
template <int QB>
__global__ __launch_bounds__(256, 1) void attn_kernel(const __bf16* __restrict__ Qg,
                                                      const __bf16* __restrict__ Kg,
                                                      const __bf16* __restrict__ Vt,
                                                      const int* __restrict__ padm,
                                                      float* __restrict__ out) {
  constexpr int Q0     = QB * 64;
  constexpr int KMAX   = (Q0 + 64 < T_) ? (Q0 + 64) : T_;   // 64,128,192,200 (causal bound)
  constexpr int KTILES = (KMAX + 15) / 16;                  // 4,8,12,13
  constexpr int KCC    = (KMAX + 31) / 32;                  // 2,4,6,7
  constexpr int KT16   = KTILES * 16;                       // 64,128,192,208
  constexpr int KP     = KCC * 32;                          // 64,128,192,224
  constexpr int VS     = KP + 8;                            // padded stride (bank spread)

  __shared__ __bf16 sK[KT16][136];
  __shared__ __bf16 sV[128][VS];       // V^T: [v][t]
  __shared__ __bf16 sP[4][16][VS];     // per-wave P transpose buffer
  __shared__ float  sMask[KT16];

  const int tid  = threadIdx.x;
  const int lane = tid & 63;
  const int w    = tid >> 6;
  const int b    = blockIdx.x;
  const int lhi  = lane >> 4, llo = lane & 15;

  // additive key mask: 0 valid, -1e30 for pad / t>=KMAX
  for (int t = tid; t < KT16; t += 256) {
    float mv = -1e30f;
    if (t < KMAX && padm[b * T_ + t] == 0) mv = 0.0f;
    sMask[t] = mv;
  }
  // stage K rows [0, KT16) (rows >= T_ clamped; they get masked anyway)
  for (int cid = tid; cid < KT16 * 16; cid += 256) {
    int t = cid >> 4, c = (cid & 15) * 8;
    int tg = (t < T_) ? t : (T_ - 1);
    *(bf16x8*)&sK[t][c] = *(const bf16x8*)(Kg + ((size_t)b * T_ + tg) * DK + c);
  }
  // stage V^T: [128][KP), zeros beyond Vt's 208 columns
  {
    constexpr int NCH = KP / 8;
    for (int cid = tid; cid < 128 * NCH; cid += 256) {
      int v = cid / NCH, t0 = (cid % NCH) * 8;
      bf16x8 val;
      if (t0 < VT_STRIDE) {
        val = *(const bf16x8*)(Vt + ((size_t)b * DK + v) * VT_STRIDE + t0);
      } else {
#pragma unroll
        for (int jz = 0; jz < 8; ++jz) val[jz] = (__bf16)0.0f;
      }
      *(bf16x8*)&sV[v][t0] = val;
    }
  }
  // zero P pad columns [KT16, KP) (only QB==3: 208..224)
  if constexpr (KT16 < KP) {
    constexpr int NC = (KP - KT16) / 8;
    for (int idx = tid; idx < 4 * 16 * NC; idx += 256) {
      int ww = idx / (16 * NC);
      int rem = idx % (16 * NC);
      int row = rem / NC, cc = (rem % NC) * 8;
      bf16x8 z;
#pragma unroll
      for (int jz = 0; jz < 8; ++jz) z[jz] = (__bf16)0.0f;
      *(bf16x8*)&sP[ww][row][KT16 + cc] = z;
    }
  }
  __syncthreads();

  // Q fragments in registers (A-frag: row = llo, k-chunk = lhi)
  const int q0w = Q0 + w * 16;
  bf16x8 qf[4];
  {
    int qrow = q0w + llo;
    if (qrow > T_ - 1) qrow = T_ - 1;
    const __bf16* qp = Qg + ((size_t)b * T_ + qrow) * DK + lhi * 8;
#pragma unroll
    for (int kk = 0; kk < 4; ++kk) qf[kk] = *(const bf16x8*)(qp + kk * 32);
  }

  // scores: S[16q x KT16] per wave, kept in registers
  float sc[KTILES][4];
  const float scale = 0.022097086912079608f;   // 1/sqrt(2048)
#pragma unroll
  for (int tt = 0; tt < KTILES; ++tt) {
    f32x4 s = {0.f, 0.f, 0.f, 0.f};
    const __bf16* kp = &sK[tt * 16 + llo][lhi * 8];
#pragma unroll
    for (int kk = 0; kk < 4; ++kk) {
      bf16x8 kf = *(const bf16x8*)(kp + kk * 32);
      s = MFMA16(qf[kk], kf, s);
    }
    const int t = tt * 16 + llo;
    const float madd = sMask[t];
#pragma unroll
    for (int r = 0; r < 4; ++r) {
      int qq = q0w + lhi * 4 + r;               // C layout: row = lhi*4+r, col = llo
      float v = fmaf(s[r], scale, madd);
      sc[tt][r] = (t > qq) ? -1e30f : v;        // overwrite-style causal mask (NaN-safe)
    }
  }

  // row softmax: reduce across the 16-lane col group per accumulator row
#pragma unroll
  for (int r = 0; r < 4; ++r) {
    float mm = -3e38f;
#pragma unroll
    for (int tt = 0; tt < KTILES; ++tt) mm = fmaxf(mm, sc[tt][r]);
#pragma unroll
    for (int off = 1; off < 16; off <<= 1) mm = fmaxf(mm, __shfl_xor(mm, off));
    float ss = 0.f;
#pragma unroll
    for (int tt = 0; tt < KTILES; ++tt) { float e = __expf(sc[tt][r] - mm); sc[tt][r] = e; ss += e; }
#pragma unroll
    for (int off = 1; off < 16; off <<= 1) ss += __shfl_xor(ss, off);
    float inv = 1.0f / ss;
#pragma unroll
    for (int tt = 0; tt < KTILES; ++tt) sc[tt][r] *= inv;
  }

  // P -> LDS (transpose through memory for the PV A-fragment)
#pragma unroll
  for (int tt = 0; tt < KTILES; ++tt) {
    int t = tt * 16 + llo;
#pragma unroll
    for (int r = 0; r < 4; ++r) sP[w][lhi * 4 + r][t] = (__bf16)sc[tt][r];
  }
  __syncthreads();

  // PV: out[16q x 128v] = P[16 x KP] @ V[KP x 128]
  f32x4 oacc[8];
#pragma unroll
  for (int vt = 0; vt < 8; ++vt) oacc[vt] = {0.f, 0.f, 0.f, 0.f};
#pragma unroll
  for (int kc = 0; kc < KCC; ++kc) {
    bf16x8 pa = *(const bf16x8*)&sP[w][llo][kc * 32 + lhi * 8];
#pragma unroll
    for (int vt = 0; vt < 8; ++vt) {
      bf16x8 vb = *(const bf16x8*)&sV[vt * 16 + llo][kc * 32 + lhi * 8];
      oacc[vt] = MFMA16(pa, vb, oacc[vt]);
    }
  }

  // write fp32 output
#pragma unroll
  for (int vt = 0; vt < 8; ++vt) {
#pragma unroll
    for (int r = 0; r < 4; ++r) {
      int qq = q0w + lhi * 4 + r;
      if (qq < T_) out[((size_t)b * T_ + qq) * DK + vt * 16 + llo] = oacc[vt][r];
    }
  }
}

extern "C" void kernel_launch(void* const* d_in, const int* in_sizes, int n_in,
                              void* d_out, int out_size, void* d_ws, size_t ws_size,
                              hipStream_t stream) {
  const float* q    = (const float*)d_in[0];
  const int*   padm = (const int*)d_in[1];
  const float* Wq   = (const float*)d_in[2];
  const float* Wk   = (const float*)d_in[3];
  const float* Wv   = (const float*)d_in[4];
  float* out        = (float*)d_out;

  char* ws = (char*)d_ws;
  __bf16* Wcat = (__bf16*)(ws + OFF_W);
  __bf16* Qb   = (__bf16*)(ws + OFF_Q);
  __bf16* Kb   = (__bf16*)(ws + OFF_K);
  __bf16* Vtb  = (__bf16*)(ws + OFF_V);

  wconv_kernel<<<768, 256, 0, stream>>>(Wq, Wk, Wv, Wcat);
  proj_kernel<<<400, 512, 0, stream>>>(q, Wcat, Qb, Kb, Vtb);
  attn_kernel<0><<<256, 256, 0, stream>>>(Qb, Kb, Vtb, padm, out);
  attn_kernel<1><<<256, 256, 0, stream>>>(Qb, Kb, Vtb, padm, out);
  attn_kernel<2><<<256, 256, 0, stream>>>(Qb, Kb, Vtb, padm, out);
  attn_kernel<3><<<256, 256, 0, stream>>>(Qb, Kb, Vtb, padm, out);
}

// Round 4
// 251.831 us; speedup vs baseline: 3.6314x; 1.0687x over previous
//
#include <hip/hip_runtime.h>

typedef __bf16 bf16x8 __attribute__((ext_vector_type(8)));
typedef __bf16 bf16x4 __attribute__((ext_vector_type(4)));
typedef float  f32x4  __attribute__((ext_vector_type(4)));

#define MFMA16(a,b,c) __builtin_amdgcn_mfma_f32_16x16x32_bf16((a),(b),(c),0,0,0)

constexpr int B_ = 256, T_ = 200, DM = 2048, DK = 128;
constexpr int VT_STRIDE = 208;      // Vt[b][v][t], t padded 200->208

// ws layout (bytes)
constexpr size_t OFF_W = 0;                       // Wcat bf16 [384][2048] = 1,572,864
constexpr size_t OFF_Q = 1572864;                 // Q bf16 [51200][128] = 13,107,200
constexpr size_t OFF_K = OFF_Q + 13107200;        // K bf16 [51200][128]
constexpr size_t OFF_V = OFF_K + 13107200;        // Vt bf16 [256][128][208] = 13,631,488

// ---------------- weight conversion: Wq|Wk|Wv fp32 -> Wcat bf16 [384][2048] ----------------
__global__ __launch_bounds__(256) void wconv_kernel(const float* __restrict__ Wq,
                                                    const float* __restrict__ Wk,
                                                    const float* __restrict__ Wv,
                                                    __bf16* __restrict__ Wcat) {
  int idx = (blockIdx.x * 256 + threadIdx.x) * 4;   // < 384*2048 = 786432
  int sel = idx >> 18;                              // /262144 -> 0,1,2
  const float* base = (sel == 0) ? Wq : (sel == 1) ? Wk : Wv;
  float4 f = *(const float4*)(base + (idx - (sel << 18)));
  bf16x4 o;
  o[0] = (__bf16)f.x; o[1] = (__bf16)f.y; o[2] = (__bf16)f.z; o[3] = (__bf16)f.w;
  *(bf16x4*)(Wcat + idx) = o;
}

// ---------------- projection GEMM: C[51200][384] = q(fp32->bf16) @ Wcat^T ----------------
// BM=128, BN=384 (full N so q HBM-read exactly once), BK=32, 512 threads (8 waves, 2m x 4n).
// Double-buffered LDS (64 KiB) + DEPTH-4 register prefetch, unrolled x4 (static set names).
// Barriers are raw `s_waitcnt lgkmcnt(0); s_barrier` -- NO vmcnt drain, so prefetch loads
// stay in flight across 3 phase boundaries (T4 counted-vmcnt via compiler-inserted waits).
__global__ __launch_bounds__(512) void proj_kernel(const float* __restrict__ q,
                                                   const __bf16* __restrict__ Wcat,
                                                   __bf16* __restrict__ Qo,
                                                   __bf16* __restrict__ Ko,
                                                   __bf16* __restrict__ Vt) {
  __shared__ __bf16 sA[2][128][32];   // 16,384 B
  __shared__ __bf16 sB[2][384][32];   // 49,152 B  (total 65,536 B)

  const int tid  = threadIdx.x;
  const int lane = tid & 63;
  const int w    = tid >> 6;
  const int wm   = w >> 2, wn = w & 3;
  const int lhi  = lane >> 4, llo = lane & 15;
  const int m0   = blockIdx.x * 128;

  f32x4 acc[4][6];
#pragma unroll
  for (int i = 0; i < 4; ++i)
#pragma unroll
    for (int j = 0; j < 6; ++j) acc[i][j] = {0.f, 0.f, 0.f, 0.f};

  // A staging: 128 rows x 32 floats / 512 threads = 8 floats (2 float4) per thread
  const int arow = tid >> 2, aseg = tid & 3;          // row, 8-float segment
  const float* aptr = q + (size_t)(m0 + arow) * DM + aseg * 8;
  // B staging: 384 rows x 32 bf16 = 1536 chunks of 8 bf16; 3 chunks per thread
  int brow[3], bcol[3];
#pragma unroll
  for (int j = 0; j < 3; ++j) {
    int c = tid + j * 512;
    brow[j] = c >> 2; bcol[j] = (c & 3) * 8;
  }

  // 4 prefetch sets (static names only -- rule #20)
  float4 a0x, a0y, a1x, a1y, a2x, a2y, a3x, a3y;
  bf16x8 b0[3], b1[3], b2[3], b3[3];

#define ISSUE(A0, A1, BB, K0)                                               \
  {                                                                         \
    const float4* s4 = (const float4*)(aptr + (K0));                        \
    A0 = s4[0]; A1 = s4[1];                                                 \
    _Pragma("unroll")                                                       \
    for (int j = 0; j < 3; ++j)                                             \
      BB[j] = *(const bf16x8*)(Wcat + (size_t)brow[j] * DM + (K0) + bcol[j]); \
  }

#define WRITETILE(A0, A1, BB, BUF)                                          \
  {                                                                         \
    bf16x8 p;                                                               \
    p[0]=(__bf16)A0.x; p[1]=(__bf16)A0.y; p[2]=(__bf16)A0.z; p[3]=(__bf16)A0.w; \
    p[4]=(__bf16)A1.x; p[5]=(__bf16)A1.y; p[6]=(__bf16)A1.z; p[7]=(__bf16)A1.w; \
    *(bf16x8*)&sA[BUF][arow][aseg * 8] = p;                                 \
    _Pragma("unroll")                                                       \
    for (int j = 0; j < 3; ++j)                                             \
      *(bf16x8*)&sB[BUF][brow[j]][bcol[j]] = BB[j];                         \
  }

#define COMPUTE(BUF)                                                        \
  {                                                                         \
    bf16x8 af[4], bfr[6];                                                   \
    _Pragma("unroll")                                                       \
    for (int i = 0; i < 4; ++i) af[i]  = *(const bf16x8*)&sA[BUF][wm * 64 + i * 16 + llo][lhi * 8]; \
    _Pragma("unroll")                                                       \
    for (int j = 0; j < 6; ++j) bfr[j] = *(const bf16x8*)&sB[BUF][wn * 96 + j * 16 + llo][lhi * 8]; \
    _Pragma("unroll")                                                       \
    for (int i = 0; i < 4; ++i)                                             \
      _Pragma("unroll")                                                     \
      for (int j = 0; j < 6; ++j) acc[i][j] = MFMA16(af[i], bfr[j], acc[i][j]); \
  }

  // Barrier WITHOUT vmcnt drain: LDS writes published via lgkmcnt(0); global
  // prefetch loads (registers only) stay outstanding across the barrier.
#define BAR()                                                               \
  {                                                                         \
    asm volatile("s_waitcnt lgkmcnt(0)" ::: "memory");                      \
    __builtin_amdgcn_s_barrier();                                           \
    asm volatile("" ::: "memory");                                          \
  }

  // prologue: fill the 4-deep pipe; stage tile 0
  ISSUE(a0x, a0y, b0, 0);
  ISSUE(a1x, a1y, b1, 32);
  ISSUE(a2x, a2y, b2, 64);
  ISSUE(a3x, a3y, b3, 96);
  WRITETILE(a0x, a0y, b0, 0);
  BAR();

  // 60 full phases (15 x 4); set s_i always holds tile with tile&3 == i
  for (int it = 0; it < 15; ++it) {
    const int t0 = it * 4;
    ISSUE(a0x, a0y, b0, (t0 + 4) * 32);
    COMPUTE(0);
    WRITETILE(a1x, a1y, b1, 1);
    BAR();
    ISSUE(a1x, a1y, b1, (t0 + 5) * 32);
    COMPUTE(1);
    WRITETILE(a2x, a2y, b2, 0);
    BAR();
    ISSUE(a2x, a2y, b2, (t0 + 6) * 32);
    COMPUTE(0);
    WRITETILE(a3x, a3y, b3, 1);
    BAR();
    ISSUE(a3x, a3y, b3, (t0 + 7) * 32);
    COMPUTE(1);
    WRITETILE(a0x, a0y, b0, 0);
    BAR();
  }
  // tail: tiles 60..63 (no more issues)
  COMPUTE(0); WRITETILE(a1x, a1y, b1, 1); BAR();
  COMPUTE(1); WRITETILE(a2x, a2y, b2, 0); BAR();
  COMPUTE(0); WRITETILE(a3x, a3y, b3, 1); BAR();
  COMPUTE(1);

#undef ISSUE
#undef WRITETILE
#undef COMPUTE
#undef BAR

  // epilogue: col<128 -> Q, <256 -> K, else -> Vt transposed per batch
#pragma unroll
  for (int i = 0; i < 4; ++i) {
#pragma unroll
    for (int r = 0; r < 4; ++r) {
      int row = m0 + wm * 64 + i * 16 + lhi * 4 + r;   // bt index, always < 51200
      int b = row / 200;
      int t = row - b * 200;
#pragma unroll
      for (int j = 0; j < 6; ++j) {
        int col = wn * 96 + j * 16 + llo;
        __bf16 bv = (__bf16)acc[i][j][r];
        if (col < 128)       Qo[(size_t)row * DK + col] = bv;
        else if (col < 256)  Ko[(size_t)row * DK + (col - 128)] = bv;
        else                 Vt[((size_t)b * DK + (col - 256)) * VT_STRIDE + t] = bv;
      }
    }
  }
}

// ---------------- attention: one WG per (batch, 64-query block), templated on block ----------------
template <int QB>
__global__ __launch_bounds__(256, 1) void attn_kernel(const __bf16* __restrict__ Qg,
                                                      const __bf16* __restrict__ Kg,
                                                      const __bf16* __restrict__ Vt,
                                                      const int* __restrict__ padm,
                                                      float* __restrict__ out) {
  constexpr int Q0     = QB * 64;
  constexpr int KMAX   = (Q0 + 64 < T_) ? (Q0 + 64) : T_;   // 64,128,192,200 (causal bound)
  constexpr int KTILES = (KMAX + 15) / 16;                  // 4,8,12,13
  constexpr int KCC    = (KMAX + 31) / 32;                  // 2,4,6,7
  constexpr int KT16   = KTILES * 16;                       // 64,128,192,208
  constexpr int KP     = KCC * 32;                          // 64,128,192,224
  constexpr int VS     = KP + 8;                            // padded stride (bank spread)

  __shared__ __bf16 sK[KT16][136];
  __shared__ __bf16 sV[128][VS];       // V^T: [v][t]
  __shared__ __bf16 sP[4][16][VS];     // per-wave P transpose buffer
  __shared__ float  sMask[KT16];

  const int tid  = threadIdx.x;
  const int lane = tid & 63;
  const int w    = tid >> 6;
  const int b    = blockIdx.x;
  const int lhi  = lane >> 4, llo = lane & 15;

  // additive key mask: 0 valid, -1e30 for pad / t>=KMAX
  for (int t = tid; t < KT16; t += 256) {
    float mv = -1e30f;
    if (t < KMAX && padm[b * T_ + t] == 0) mv = 0.0f;
    sMask[t] = mv;
  }
  // stage K rows [0, KT16) (rows >= T_ clamped; they get masked anyway)
  for (int cid = tid; cid < KT16 * 16; cid += 256) {
    int t = cid >> 4, c = (cid & 15) * 8;
    int tg = (t < T_) ? t : (T_ - 1);
    *(bf16x8*)&sK[t][c] = *(const bf16x8*)(Kg + ((size_t)b * T_ + tg) * DK + c);
  }
  // stage V^T: [128][KP), zeros beyond Vt's 208 columns
  {
    constexpr int NCH = KP / 8;
    for (int cid = tid; cid < 128 * NCH; cid += 256) {
      int v = cid / NCH, t0 = (cid % NCH) * 8;
      bf16x8 val;
      if (t0 < VT_STRIDE) {
        val = *(const bf16x8*)(Vt + ((size_t)b * DK + v) * VT_STRIDE + t0);
      } else {
#pragma unroll
        for (int jz = 0; jz < 8; ++jz) val[jz] = (__bf16)0.0f;
      }
      *(bf16x8*)&sV[v][t0] = val;
    }
  }
  // zero P pad columns [KT16, KP) (only QB==3: 208..224)
  if constexpr (KT16 < KP) {
    constexpr int NC = (KP - KT16) / 8;
    for (int idx = tid; idx < 4 * 16 * NC; idx += 256) {
      int ww = idx / (16 * NC);
      int rem = idx % (16 * NC);
      int row = rem / NC, cc = (rem % NC) * 8;
      bf16x8 z;
#pragma unroll
      for (int jz = 0; jz < 8; ++jz) z[jz] = (__bf16)0.0f;
      *(bf16x8*)&sP[ww][row][KT16 + cc] = z;
    }
  }
  __syncthreads();

  // Q fragments in registers (A-frag: row = llo, k-chunk = lhi)
  const int q0w = Q0 + w * 16;
  bf16x8 qf[4];
  {
    int qrow = q0w + llo;
    if (qrow > T_ - 1) qrow = T_ - 1;
    const __bf16* qp = Qg + ((size_t)b * T_ + qrow) * DK + lhi * 8;
#pragma unroll
    for (int kk = 0; kk < 4; ++kk) qf[kk] = *(const bf16x8*)(qp + kk * 32);
  }

  // scores: S[16q x KT16] per wave, kept in registers
  float sc[KTILES][4];
  const float scale = 0.022097086912079608f;   // 1/sqrt(2048)
#pragma unroll
  for (int tt = 0; tt < KTILES; ++tt) {
    f32x4 s = {0.f, 0.f, 0.f, 0.f};
    const __bf16* kp = &sK[tt * 16 + llo][lhi * 8];
#pragma unroll
    for (int kk = 0; kk < 4; ++kk) {
      bf16x8 kf = *(const bf16x8*)(kp + kk * 32);
      s = MFMA16(qf[kk], kf, s);
    }
    const int t = tt * 16 + llo;
    const float madd = sMask[t];
#pragma unroll
    for (int r = 0; r < 4; ++r) {
      int qq = q0w + lhi * 4 + r;               // C layout: row = lhi*4+r, col = llo
      float v = fmaf(s[r], scale, madd);
      sc[tt][r] = (t > qq) ? -1e30f : v;        // overwrite-style causal mask (NaN-safe)
    }
  }

  // row softmax: reduce across the 16-lane col group per accumulator row
#pragma unroll
  for (int r = 0; r < 4; ++r) {
    float mm = -3e38f;
#pragma unroll
    for (int tt = 0; tt < KTILES; ++tt) mm = fmaxf(mm, sc[tt][r]);
#pragma unroll
    for (int off = 1; off < 16; off <<= 1) mm = fmaxf(mm, __shfl_xor(mm, off));
    float ss = 0.f;
#pragma unroll
    for (int tt = 0; tt < KTILES; ++tt) { float e = __expf(sc[tt][r] - mm); sc[tt][r] = e; ss += e; }
#pragma unroll
    for (int off = 1; off < 16; off <<= 1) ss += __shfl_xor(ss, off);
    float inv = 1.0f / ss;
#pragma unroll
    for (int tt = 0; tt < KTILES; ++tt) sc[tt][r] *= inv;
  }

  // P -> LDS (transpose through memory for the PV A-fragment)
#pragma unroll
  for (int tt = 0; tt < KTILES; ++tt) {
    int t = tt * 16 + llo;
#pragma unroll
    for (int r = 0; r < 4; ++r) sP[w][lhi * 4 + r][t] = (__bf16)sc[tt][r];
  }
  __syncthreads();

  // PV: out[16q x 128v] = P[16 x KP] @ V[KP x 128]
  f32x4 oacc[8];
#pragma unroll
  for (int vt = 0; vt < 8; ++vt) oacc[vt] = {0.f, 0.f, 0.f, 0.f};
#pragma unroll
  for (int kc = 0; kc < KCC; ++kc) {
    bf16x8 pa = *(const bf16x8*)&sP[w][llo][kc * 32 + lhi * 8];
#pragma unroll
    for (int vt = 0; vt < 8; ++vt) {
      bf16x8 vb = *(const bf16x8*)&sV[vt * 16 + llo][kc * 32 + lhi * 8];
      oacc[vt] = MFMA16(pa, vb, oacc[vt]);
    }
  }

  // write fp32 output
#pragma unroll
  for (int vt = 0; vt < 8; ++vt) {
#pragma unroll
    for (int r = 0; r < 4; ++r) {
      int qq = q0w + lhi * 4 + r;
      if (qq < T_) out[((size_t)b * T_ + qq) * DK + vt * 16 + llo] = oacc[vt][r];
    }
  }
}

extern "C" void kernel_launch(void* const* d_in, const int* in_sizes, int n_in,
                              void* d_out, int out_size, void* d_ws, size_t ws_size,
                              hipStream_t stream) {
  const float* q    = (const float*)d_in[0];
  const int*   padm = (const int*)d_in[1];
  const float* Wq   = (const float*)d_in[2];
  const float* Wk   = (const float*)d_in[3];
  const float* Wv   = (const float*)d_in[4];
  float* out        = (float*)d_out;

  char* ws = (char*)d_ws;
  __bf16* Wcat = (__bf16*)(ws + OFF_W);
  __bf16* Qb   = (__bf16*)(ws + OFF_Q);
  __bf16* Kb   = (__bf16*)(ws + OFF_K);
  __bf16* Vtb  = (__bf16*)(ws + OFF_V);

  wconv_kernel<<<768, 256, 0, stream>>>(Wq, Wk, Wv, Wcat);
  proj_kernel<<<400, 512, 0, stream>>>(q, Wcat, Qb, Kb, Vtb);
  attn_kernel<0><<<256, 256, 0, stream>>>(Qb, Kb, Vtb, padm, out);
  attn_kernel<1><<<256, 256, 0, stream>>>(Qb, Kb, Vtb, padm, out);
  attn_kernel<2><<<256, 256, 0, stream>>>(Qb, Kb, Vtb, padm, out);
  attn_kernel<3><<<256, 256, 0, stream>>>(Qb, Kb, Vtb, padm, out);
}